// Round 6
// baseline (71.070 us; speedup 1.0000x reference)
//
#include <hip/hip_runtime.h>

typedef float f32x4 __attribute__((ext_vector_type(4)));
typedef short s16x8 __attribute__((ext_vector_type(8)));

#if __has_builtin(__builtin_amdgcn_exp2f)
#define EXP2F(x) __builtin_amdgcn_exp2f(x)
#else
#define EXP2F(x) __expf((x) * 0.6931471805599453f)
#endif

__device__ inline unsigned short bf16_rne(float v) {
    unsigned u = __float_as_uint(v);
    u += 0x7FFFu + ((u >> 16) & 1u);
    return (unsigned short)(u >> 16);
}

// Single fused kernel: out[i,j] = exp2( nx[i] + ny[j] + two_s*(x_i . y_j) )
// 128x128 tile / 256-thread block, 4 waves 2x2.
// - Panels staged into LDS once per block directly from fp32 (inline bf16
//   hi/lo split), XOR-swizzled; shared by all 4 waves.
// - Row norms computed during staging (8-lane shfl reduce -> 1KB LDS),
//   prescaled by -gamma*log2e. No separate prologue kernel, no ws.
// - 3 split-MFMAs (hh,hl,lh) per k-step, fp32 accumulate.
// - Epilogue: per-wave LDS transpose bounce (overlaid on dead staging
//   buffer) -> every global store is dwordx4 = 4 rows x 256B full lines.
#define LROW 68
__global__ __launch_bounds__(256, 2) void rbf_fused(
        const float* __restrict__ x, const float* __restrict__ y,
        const float* __restrict__ gamma_p,
        float* __restrict__ out, int N, int M, int nbm, int nbn) {
    __shared__ char smem[65536];     // Ah@0 Al@16K Bh@32K Bl@48K; epilogue overlay
    __shared__ float nrmAB[256];     // [0:128) = -s*|x_row|^2, [128:256) = -s*|y_row|^2

    // XCD-chunked bijective swizzle (HW round-robins blockIdx -> XCD):
    // XCD k owns 8 contiguous x-panels; bm fastest within the chunk.
    int bm, bn;
    const int nwg = nbm * nbn;
    if ((nwg & 7) == 0 && (nbm & 7) == 0) {
        const int xcd = blockIdx.x & 7;
        const int lo  = blockIdx.x >> 3;
        const int bmPerX = nbm >> 3;
        bn = lo / bmPerX;
        bm = xcd * bmPerX + (lo - bn * bmPerX);
    } else {
        bm = blockIdx.x / nbn;
        bn = blockIdx.x - bm * nbn;
    }

    const int tid = threadIdx.x;
    const int lane = tid & 63;
    const int wid = tid >> 6;
    const int wr = wid >> 1, wc = wid & 1;
    const int brow = bm * 128 + wr * 64;
    const int bcol = bn * 128 + wc * 64;
    const int l15 = lane & 15;
    const int lg  = lane >> 4;          // 0..3

    const float g = *gamma_p;
    const float negs = -g * 1.4426950408889634f;
    const float two_s = 2.0f * g * 1.4426950408889634f;

    f32x4 acc[4][4];
    #pragma unroll
    for (int i = 0; i < 4; ++i)
        #pragma unroll
        for (int j = 0; j < 4; ++j)
            #pragma unroll
            for (int e = 0; e < 4; ++e)
                acc[i][j][e] = 0.0f;

    // --- stage panels + fused norms ---
    // unit u (8 floats of one row): u<1024: x panel, else y; v=u&1023,
    // row=v>>3, kc=v&7. hi byte = base + row*128 + ((kc^(row&7))<<4), lo +16K.
    // Row norm: 8 lanes (kc=0..7) hold the row -> 3x shfl_xor reduce.
    {
        const float* srcx = x + (size_t)bm * 128 * 64;
        const float* srcy = y + (size_t)bn * 128 * 64;
        #pragma unroll
        for (int it = 0; it < 8; ++it) {
            const int u = it * 256 + tid;
            const int isy = it >> 2;             // compile-time
            const int v = u & 1023;
            const int row = v >> 3, kc = v & 7;
            const float* s = (isy ? srcy : srcx) + (size_t)row * 64 + kc * 8;
            f32x4 t0 = *(const f32x4*)s;
            f32x4 t1 = *(const f32x4*)(s + 4);
            s16x8 h, l;
            #pragma unroll
            for (int j = 0; j < 4; ++j) {
                unsigned short hb = bf16_rne(t0[j]);
                float hf = __uint_as_float((unsigned)hb << 16);
                h[j] = (short)hb; l[j] = (short)bf16_rne(t0[j] - hf);
                hb = bf16_rne(t1[j]);
                hf = __uint_as_float((unsigned)hb << 16);
                h[4+j] = (short)hb; l[4+j] = (short)bf16_rne(t1[j] - hf);
            }
            const int dst = (isy << 15) + row * 128 + ((kc ^ (row & 7)) << 4);
            *(s16x8*)(smem + dst) = h;
            *(s16x8*)(smem + dst + 16384) = l;

            float sn = t0[0]*t0[0] + t0[1]*t0[1] + t0[2]*t0[2] + t0[3]*t0[3]
                     + t1[0]*t1[0] + t1[1]*t1[1] + t1[2]*t1[2] + t1[3]*t1[3];
            sn += __shfl_xor(sn, 1);
            sn += __shfl_xor(sn, 2);
            sn += __shfl_xor(sn, 4);
            if (kc == 0)
                nrmAB[(isy << 7) + row] = negs * sn;
        }
    }
    __syncthreads();

    s16x8 ah[4], al[4], bh[4], bl[4];
    #pragma unroll
    for (int k0 = 0; k0 < 64; k0 += 32) {
        const int kc = (k0 >> 3) + lg;
        #pragma unroll
        for (int mf = 0; mf < 4; ++mf) {
            const int arow = wr * 64 + mf * 16 + l15;
            const int off = arow * 128 + ((kc ^ (arow & 7)) << 4);
            ah[mf] = *(const s16x8*)(smem + off);
            al[mf] = *(const s16x8*)(smem + 16384 + off);
        }
        #pragma unroll
        for (int nf = 0; nf < 4; ++nf) {
            const int brw = wc * 64 + nf * 16 + l15;
            const int off = brw * 128 + ((kc ^ (brw & 7)) << 4);
            bh[nf] = *(const s16x8*)(smem + 32768 + off);
            bl[nf] = *(const s16x8*)(smem + 49152 + off);
        }
        #pragma unroll
        for (int mf = 0; mf < 4; ++mf)
            #pragma unroll
            for (int nf = 0; nf < 4; ++nf) {
                acc[mf][nf] = __builtin_amdgcn_mfma_f32_16x16x32_bf16(ah[mf], bh[nf], acc[mf][nf], 0, 0, 0);
                acc[mf][nf] = __builtin_amdgcn_mfma_f32_16x16x32_bf16(ah[mf], bl[nf], acc[mf][nf], 0, 0, 0);
                acc[mf][nf] = __builtin_amdgcn_mfma_f32_16x16x32_bf16(al[mf], bh[nf], acc[mf][nf], 0, 0, 0);
            }
    }
    __syncthreads();   // staging buffer dead; safe to overlay epilogue bounce

    float yn[4];
    #pragma unroll
    for (int nf = 0; nf < 4; ++nf)
        yn[nf] = nrmAB[128 + wc * 64 + nf * 16 + l15];

    float* wl = (float*)smem + wid * 16 * LROW;   // per-wave 4.25KB overlay

    #pragma unroll
    for (int mf = 0; mf < 4; ++mf) {
        // C/D layout: col = lane&15 (within 16), row = lg*4 + j
        float xn[4];
        #pragma unroll
        for (int j = 0; j < 4; ++j)
            xn[j] = nrmAB[wr * 64 + mf * 16 + lg * 4 + j];

        #pragma unroll
        for (int nf = 0; nf < 4; ++nf) {
            const int c = nf * 16 + l15;
            #pragma unroll
            for (int j = 0; j < 4; ++j) {
                const float d = fmaf(two_s, acc[mf][nf][j], xn[j] + yn[nf]);
                wl[(lg * 4 + j) * LROW + c] = EXP2F(d);
            }
        }
        // same-wave exchange: lgkmcnt ordering only, no barrier needed
        #pragma unroll
        for (int t = 0; t < 4; ++t) {
            const int r = t * 4 + lg;
            f32x4 v = *(const f32x4*)&wl[r * LROW + l15 * 4];
            float* dst = out + (size_t)(brow + mf * 16 + r) * M + bcol + l15 * 4;
            *(f32x4*)dst = v;
        }
    }
}

extern "C" void kernel_launch(void* const* d_in, const int* in_sizes, int n_in,
                              void* d_out, int out_size, void* d_ws, size_t ws_size,
                              hipStream_t stream) {
    const float* x = (const float*)d_in[0];
    const float* y = (const float*)d_in[1];
    const float* gamma_p = (const float*)d_in[2];
    float* out = (float*)d_out;

    const int D = 64;
    const int N = in_sizes[0] / D;
    const int M = in_sizes[1] / D;

    const int nbm = N / 128, nbn = M / 128;
    rbf_fused<<<nbm * nbn, 256, 0, stream>>>(x, y, gamma_p, out, N, M, nbm, nbn);
}

// Round 7
// 59.312 us; speedup vs baseline: 1.1982x; 1.1982x over previous
//
#include <hip/hip_runtime.h>

typedef float f32x4 __attribute__((ext_vector_type(4)));
typedef short s16x8 __attribute__((ext_vector_type(8)));

#if __has_builtin(__builtin_amdgcn_exp2f)
#define EXP2F(x) __builtin_amdgcn_exp2f(x)
#else
#define EXP2F(x) __expf((x) * 0.6931471805599453f)
#endif

__device__ inline unsigned short bf16_rne(float v) {
    unsigned u = __float_as_uint(v);
    u += 0x7FFFu + ((u >> 16) & 1u);
    return (unsigned short)(u >> 16);
}

// ---------------- Prologue ----------------
// Packs x and y into per-128-row-panel contiguous, PRE-SWIZZLED bf16 hi/lo
// arrays so the main kernel can stage with linear global_load_lds.
// Panel layout (32KB per panel, 16B units): unit u:
//   u<1024 : hi, row=u>>3, kc_swz=u&7  (true kc = kc_swz ^ (row&7))
//   u>=1024: lo, same minus 1024.
// Also writes nrm[r] = -g*log2e*|row|^2 (x rows then y rows).
// 32 rows / 256-thread block, 8 threads per row (one 8-elem chunk each).
__global__ __launch_bounds__(256) void rbf_pack(
        const float* __restrict__ x, const float* __restrict__ y,
        const float* __restrict__ gamma_p, float* __restrict__ nrm,
        unsigned short* __restrict__ xpk, unsigned short* __restrict__ ypk,
        int N, int M) {
    const int t = threadIdx.x;
    const int r = blockIdx.x * 32 + (t >> 3);
    const int c = t & 7;                    // chunk 0..7
    if (r >= N + M) return;
    const int isX = r < N;
    const int rr = isX ? r : (r - N);
    const float* src = (isX ? x : y) + (size_t)rr * 64 + c * 8;
    f32x4 t0 = *(const f32x4*)src;
    f32x4 t1 = *(const f32x4*)(src + 4);

    s16x8 h, l;
    #pragma unroll
    for (int j = 0; j < 4; ++j) {
        unsigned short hb = bf16_rne(t0[j]);
        float hf = __uint_as_float((unsigned)hb << 16);
        h[j] = (short)hb; l[j] = (short)bf16_rne(t0[j] - hf);
        hb = bf16_rne(t1[j]);
        hf = __uint_as_float((unsigned)hb << 16);
        h[4+j] = (short)hb; l[4+j] = (short)bf16_rne(t1[j] - hf);
    }

    float sn = t0[0]*t0[0] + t0[1]*t0[1] + t0[2]*t0[2] + t0[3]*t0[3]
             + t1[0]*t1[0] + t1[1]*t1[1] + t1[2]*t1[2] + t1[3]*t1[3];
    sn += __shfl_xor(sn, 1);
    sn += __shfl_xor(sn, 2);
    sn += __shfl_xor(sn, 4);
    if (c == 0)
        nrm[r] = -(*gamma_p) * 1.4426950408889634f * sn;

    const int prow = rr & 127;
    const size_t pbase = (size_t)(rr >> 7) * 2048;          // panel base, units
    const size_t uh = pbase + prow * 8 + (c ^ (prow & 7));  // hi unit
    unsigned short* pk = isX ? xpk : ypk;
    *(s16x8*)(pk + uh * 8) = h;                 // unit = 8 shorts = 16B
    *(s16x8*)(pk + (uh + 1024) * 8) = l;
}

// ---------------- Main ----------------
// out[i,j] = exp2( nx[i] + ny[j] + two_s*(x_i . y_j) )
// 128x128 tile / 256-thread block, 4 waves 2x2.
// Staging: 16x global_load_lds_dwordx4 linear block-copy of pre-swizzled
// panels (zero VALU on the load->LDS path). LDS image identical to R4:
// Ah@0 Al@16K Bh@32K Bl@48K, row*128 + ((kc^(row&7))<<4).
// Epilogue: per-wave LDS transpose bounce (overlay) -> dwordx4 full-line stores.
#define LROW 68
__global__ __launch_bounds__(256, 2) void rbf_main(
        const unsigned short* __restrict__ xpk, const unsigned short* __restrict__ ypk,
        const float* __restrict__ gamma_p, const float* __restrict__ nrm,
        float* __restrict__ out, int N, int M, int nbm, int nbn) {
    __shared__ char smem[65536];

    int bm, bn;
    const int nwg = nbm * nbn;
    if ((nwg & 7) == 0 && (nbm & 7) == 0) {
        const int xcd = blockIdx.x & 7;
        const int lo  = blockIdx.x >> 3;
        const int bmPerX = nbm >> 3;
        bn = lo / bmPerX;
        bm = xcd * bmPerX + (lo - bn * bmPerX);
    } else {
        bm = blockIdx.x / nbn;
        bn = blockIdx.x - bm * nbn;
    }

    const int tid = threadIdx.x;
    const int lane = tid & 63;
    const int wid = tid >> 6;
    const int wr = wid >> 1, wc = wid & 1;
    const int brow = bm * 128 + wr * 64;
    const int bcol = bn * 128 + wc * 64;
    const int l15 = lane & 15;
    const int lg  = lane >> 4;

    f32x4 acc[4][4];
    #pragma unroll
    for (int i = 0; i < 4; ++i)
        #pragma unroll
        for (int j = 0; j < 4; ++j)
            #pragma unroll
            for (int e = 0; e < 4; ++e)
                acc[i][j][e] = 0.0f;

    // --- staging: pure linear copy, global -> LDS direct ---
    {
        const char* srcA = (const char*)xpk + (size_t)bm * 32768;
        const char* srcB = (const char*)ypk + (size_t)bn * 32768;
        #pragma unroll
        for (int it = 0; it < 16; ++it) {
            const int isB = it >> 3;                       // compile-time
            const int local = (it & 7) * 4096 + wid * 1024;
            const char* src = (isB ? srcB : srcA) + local + lane * 16;
            char* dst = smem + isB * 32768 + local;        // wave-uniform; HW adds lane*16
#if __has_builtin(__builtin_amdgcn_global_load_lds)
            __builtin_amdgcn_global_load_lds(
                (const __attribute__((address_space(1))) void*)src,
                (__attribute__((address_space(3))) void*)dst, 16, 0, 0);
#else
            *(s16x8*)(dst + lane * 16) = *(const s16x8*)src;
#endif
        }
    }
    __syncthreads();

    s16x8 ah[4], al[4], bh[4], bl[4];
    #pragma unroll
    for (int k0 = 0; k0 < 64; k0 += 32) {
        const int kc = (k0 >> 3) + lg;
        #pragma unroll
        for (int mf = 0; mf < 4; ++mf) {
            const int arow = wr * 64 + mf * 16 + l15;
            const int off = arow * 128 + ((kc ^ (arow & 7)) << 4);
            ah[mf] = *(const s16x8*)(smem + off);
            al[mf] = *(const s16x8*)(smem + 16384 + off);
        }
        #pragma unroll
        for (int nf = 0; nf < 4; ++nf) {
            const int brw = wc * 64 + nf * 16 + l15;
            const int off = brw * 128 + ((kc ^ (brw & 7)) << 4);
            bh[nf] = *(const s16x8*)(smem + 32768 + off);
            bl[nf] = *(const s16x8*)(smem + 49152 + off);
        }
        #pragma unroll
        for (int mf = 0; mf < 4; ++mf)
            #pragma unroll
            for (int nf = 0; nf < 4; ++nf) {
                acc[mf][nf] = __builtin_amdgcn_mfma_f32_16x16x32_bf16(ah[mf], bh[nf], acc[mf][nf], 0, 0, 0);
                acc[mf][nf] = __builtin_amdgcn_mfma_f32_16x16x32_bf16(ah[mf], bl[nf], acc[mf][nf], 0, 0, 0);
                acc[mf][nf] = __builtin_amdgcn_mfma_f32_16x16x32_bf16(al[mf], bh[nf], acc[mf][nf], 0, 0, 0);
            }
    }
    __syncthreads();   // staging buffer dead; overlay epilogue bounce

    const float g = *gamma_p;
    const float two_s = 2.0f * g * 1.4426950408889634f;
    const float* nx = nrm;
    const float* ny = nrm + N;

    float yn[4];
    #pragma unroll
    for (int nf = 0; nf < 4; ++nf)
        yn[nf] = ny[bcol + nf * 16 + l15];

    float* wl = (float*)smem + wid * 16 * LROW;

    #pragma unroll
    for (int mf = 0; mf < 4; ++mf) {
        // C/D layout: col = lane&15, row = lg*4 + j
        float xn[4];
        #pragma unroll
        for (int j = 0; j < 4; ++j)
            xn[j] = nx[brow + mf * 16 + lg * 4 + j];

        #pragma unroll
        for (int nf = 0; nf < 4; ++nf) {
            const int c = nf * 16 + l15;
            #pragma unroll
            for (int j = 0; j < 4; ++j) {
                const float d = fmaf(two_s, acc[mf][nf][j], xn[j] + yn[nf]);
                wl[(lg * 4 + j) * LROW + c] = EXP2F(d);
            }
        }
        #pragma unroll
        for (int t = 0; t < 4; ++t) {
            const int r = t * 4 + lg;
            f32x4 v = *(const f32x4*)&wl[r * LROW + l15 * 4];
            float* dst = out + (size_t)(brow + mf * 16 + r) * M + bcol + l15 * 4;
            *(f32x4*)dst = v;
        }
    }
}

// Fallback (ws too small): R6-style fully fused kernel, no workspace.
__global__ __launch_bounds__(256, 2) void rbf_fused_nows(
        const float* __restrict__ x, const float* __restrict__ y,
        const float* __restrict__ gamma_p,
        float* __restrict__ out, int N, int M, int nbm, int nbn) {
    __shared__ char smem[65536];
    __shared__ float nrmAB[256];

    int bm, bn;
    const int nwg = nbm * nbn;
    if ((nwg & 7) == 0 && (nbm & 7) == 0) {
        const int xcd = blockIdx.x & 7;
        const int lo  = blockIdx.x >> 3;
        const int bmPerX = nbm >> 3;
        bn = lo / bmPerX;
        bm = xcd * bmPerX + (lo - bn * bmPerX);
    } else {
        bm = blockIdx.x / nbn;
        bn = blockIdx.x - bm * nbn;
    }

    const int tid = threadIdx.x;
    const int lane = tid & 63;
    const int wid = tid >> 6;
    const int wr = wid >> 1, wc = wid & 1;
    const int brow = bm * 128 + wr * 64;
    const int bcol = bn * 128 + wc * 64;
    const int l15 = lane & 15;
    const int lg  = lane >> 4;

    const float g = *gamma_p;
    const float negs = -g * 1.4426950408889634f;
    const float two_s = 2.0f * g * 1.4426950408889634f;

    f32x4 acc[4][4];
    #pragma unroll
    for (int i = 0; i < 4; ++i)
        #pragma unroll
        for (int j = 0; j < 4; ++j)
            #pragma unroll
            for (int e = 0; e < 4; ++e)
                acc[i][j][e] = 0.0f;

    {
        const float* srcx = x + (size_t)bm * 128 * 64;
        const float* srcy = y + (size_t)bn * 128 * 64;
        #pragma unroll
        for (int it = 0; it < 8; ++it) {
            const int u = it * 256 + tid;
            const int isy = it >> 2;
            const int v = u & 1023;
            const int row = v >> 3, kc = v & 7;
            const float* s = (isy ? srcy : srcx) + (size_t)row * 64 + kc * 8;
            f32x4 t0 = *(const f32x4*)s;
            f32x4 t1 = *(const f32x4*)(s + 4);
            s16x8 h, l;
            #pragma unroll
            for (int j = 0; j < 4; ++j) {
                unsigned short hb = bf16_rne(t0[j]);
                float hf = __uint_as_float((unsigned)hb << 16);
                h[j] = (short)hb; l[j] = (short)bf16_rne(t0[j] - hf);
                hb = bf16_rne(t1[j]);
                hf = __uint_as_float((unsigned)hb << 16);
                h[4+j] = (short)hb; l[4+j] = (short)bf16_rne(t1[j] - hf);
            }
            const int dst = (isy << 15) + row * 128 + ((kc ^ (row & 7)) << 4);
            *(s16x8*)(smem + dst) = h;
            *(s16x8*)(smem + dst + 16384) = l;
            float sn = t0[0]*t0[0] + t0[1]*t0[1] + t0[2]*t0[2] + t0[3]*t0[3]
                     + t1[0]*t1[0] + t1[1]*t1[1] + t1[2]*t1[2] + t1[3]*t1[3];
            sn += __shfl_xor(sn, 1);
            sn += __shfl_xor(sn, 2);
            sn += __shfl_xor(sn, 4);
            if (kc == 0) nrmAB[(isy << 7) + row] = negs * sn;
        }
    }
    __syncthreads();

    s16x8 ah[4], al[4], bh[4], bl[4];
    #pragma unroll
    for (int k0 = 0; k0 < 64; k0 += 32) {
        const int kc = (k0 >> 3) + lg;
        #pragma unroll
        for (int mf = 0; mf < 4; ++mf) {
            const int arow = wr * 64 + mf * 16 + l15;
            const int off = arow * 128 + ((kc ^ (arow & 7)) << 4);
            ah[mf] = *(const s16x8*)(smem + off);
            al[mf] = *(const s16x8*)(smem + 16384 + off);
        }
        #pragma unroll
        for (int nf = 0; nf < 4; ++nf) {
            const int brw = wc * 64 + nf * 16 + l15;
            const int off = brw * 128 + ((kc ^ (brw & 7)) << 4);
            bh[nf] = *(const s16x8*)(smem + 32768 + off);
            bl[nf] = *(const s16x8*)(smem + 49152 + off);
        }
        #pragma unroll
        for (int mf = 0; mf < 4; ++mf)
            #pragma unroll
            for (int nf = 0; nf < 4; ++nf) {
                acc[mf][nf] = __builtin_amdgcn_mfma_f32_16x16x32_bf16(ah[mf], bh[nf], acc[mf][nf], 0, 0, 0);
                acc[mf][nf] = __builtin_amdgcn_mfma_f32_16x16x32_bf16(ah[mf], bl[nf], acc[mf][nf], 0, 0, 0);
                acc[mf][nf] = __builtin_amdgcn_mfma_f32_16x16x32_bf16(al[mf], bh[nf], acc[mf][nf], 0, 0, 0);
            }
    }
    __syncthreads();

    float yn[4];
    #pragma unroll
    for (int nf = 0; nf < 4; ++nf)
        yn[nf] = nrmAB[128 + wc * 64 + nf * 16 + l15];

    float* wl = (float*)smem + wid * 16 * LROW;
    #pragma unroll
    for (int mf = 0; mf < 4; ++mf) {
        float xn[4];
        #pragma unroll
        for (int j = 0; j < 4; ++j)
            xn[j] = nrmAB[wr * 64 + mf * 16 + lg * 4 + j];
        #pragma unroll
        for (int nf = 0; nf < 4; ++nf) {
            const int c = nf * 16 + l15;
            #pragma unroll
            for (int j = 0; j < 4; ++j) {
                const float d = fmaf(two_s, acc[mf][nf][j], xn[j] + yn[nf]);
                wl[(lg * 4 + j) * LROW + c] = EXP2F(d);
            }
        }
        #pragma unroll
        for (int t = 0; t < 4; ++t) {
            const int r = t * 4 + lg;
            f32x4 v = *(const f32x4*)&wl[r * LROW + l15 * 4];
            float* dst = out + (size_t)(brow + mf * 16 + r) * M + bcol + l15 * 4;
            *(f32x4*)dst = v;
        }
    }
}

extern "C" void kernel_launch(void* const* d_in, const int* in_sizes, int n_in,
                              void* d_out, int out_size, void* d_ws, size_t ws_size,
                              hipStream_t stream) {
    const float* x = (const float*)d_in[0];
    const float* y = (const float*)d_in[1];
    const float* gamma_p = (const float*)d_in[2];
    float* out = (float*)d_out;

    const int D = 64;
    const int N = in_sizes[0] / D;
    const int M = in_sizes[1] / D;
    const int nbm = N / 128, nbn = M / 128;

    // ws layout: [nrm: (N+M) f32][xpk: N*128 u16][ypk: M*128 u16] (16B aligned)
    char* wsb = (char*)d_ws;
    float* nrm = (float*)wsb;
    size_t off = ((size_t)(N + M) * 4 + 15) & ~(size_t)15;
    unsigned short* xpk = (unsigned short*)(wsb + off); off += (size_t)N * 128 * 2;
    unsigned short* ypk = (unsigned short*)(wsb + off); off += (size_t)M * 128 * 2;

    if (ws_size >= off) {
        const int rows = N + M;
        rbf_pack<<<(rows + 31) / 32, 256, 0, stream>>>(x, y, gamma_p, nrm, xpk, ypk, N, M);
        rbf_main<<<nbm * nbn, 256, 0, stream>>>(xpk, ypk, gamma_p, nrm, out, N, M, nbm, nbn);
    } else {
        rbf_fused_nows<<<nbm * nbn, 256, 0, stream>>>(x, y, gamma_p, out, N, M, nbm, nbn);
    }
}

// Round 8
// 52.228 us; speedup vs baseline: 1.3608x; 1.1356x over previous
//
#include <hip/hip_runtime.h>

typedef float f32x4 __attribute__((ext_vector_type(4)));
typedef short s16x8 __attribute__((ext_vector_type(8)));

#if __has_builtin(__builtin_amdgcn_exp2f)
#define EXP2F(x) __builtin_amdgcn_exp2f(x)
#else
#define EXP2F(x) __expf((x) * 0.6931471805599453f)
#endif

__device__ inline unsigned short bf16_rne(float v) {
    unsigned u = __float_as_uint(v);
    u += 0x7FFFu + ((u >> 16) & 1u);
    return (unsigned short)(u >> 16);
}

// ---------------- Prologue ----------------
// Packs x and y into per-128-row-panel contiguous, PRE-SWIZZLED bf16 hi/lo
// arrays (linear global_load_lds reproduces the swizzled LDS image).
// Panel (32KB, 16B units): u<1024: hi, row=u>>3, kc_swz=u&7 (kc=kc_swz^(row&7));
// u>=1024: lo. Also nrm[r] = -g*log2e*|row|^2 (x rows then y rows).
__global__ __launch_bounds__(256) void rbf_pack(
        const float* __restrict__ x, const float* __restrict__ y,
        const float* __restrict__ gamma_p, float* __restrict__ nrm,
        unsigned short* __restrict__ xpk, unsigned short* __restrict__ ypk,
        int N, int M) {
    const int t = threadIdx.x;
    const int r = blockIdx.x * 32 + (t >> 3);
    const int c = t & 7;
    if (r >= N + M) return;
    const int isX = r < N;
    const int rr = isX ? r : (r - N);
    const float* src = (isX ? x : y) + (size_t)rr * 64 + c * 8;
    f32x4 t0 = *(const f32x4*)src;
    f32x4 t1 = *(const f32x4*)(src + 4);

    s16x8 h, l;
    #pragma unroll
    for (int j = 0; j < 4; ++j) {
        unsigned short hb = bf16_rne(t0[j]);
        float hf = __uint_as_float((unsigned)hb << 16);
        h[j] = (short)hb; l[j] = (short)bf16_rne(t0[j] - hf);
        hb = bf16_rne(t1[j]);
        hf = __uint_as_float((unsigned)hb << 16);
        h[4+j] = (short)hb; l[4+j] = (short)bf16_rne(t1[j] - hf);
    }

    float sn = t0[0]*t0[0] + t0[1]*t0[1] + t0[2]*t0[2] + t0[3]*t0[3]
             + t1[0]*t1[0] + t1[1]*t1[1] + t1[2]*t1[2] + t1[3]*t1[3];
    sn += __shfl_xor(sn, 1);
    sn += __shfl_xor(sn, 2);
    sn += __shfl_xor(sn, 4);
    if (c == 0)
        nrm[r] = -(*gamma_p) * 1.4426950408889634f * sn;

    const int prow = rr & 127;
    const size_t pbase = (size_t)(rr >> 7) * 2048;
    const size_t uh = pbase + prow * 8 + (c ^ (prow & 7));
    unsigned short* pk = isX ? xpk : ypk;
    *(s16x8*)(pk + uh * 8) = h;
    *(s16x8*)(pk + (uh + 1024) * 8) = l;
}

#define LROW 68
#define NT 8

// ---------------- Persistent main ----------------
// Each block: one bm panel (A in REGISTERS, loaded once) x NT consecutive bn
// tiles. B panels double-buffered in LDS (2x32KB) via linear global_load_lds
// of the pre-swizzled pack. 2-phase pipeline with counted vmcnt(16): output
// stores stay in flight across iterations (never drained in the loop).
__global__ __launch_bounds__(256, 2) void rbf_persist(
        const unsigned short* __restrict__ xpk, const unsigned short* __restrict__ ypk,
        const float* __restrict__ gamma_p, const float* __restrict__ nrm,
        float* __restrict__ out, int N, int M, int nbm, int nbn) {
    __shared__ char smem[65536];   // buf0 @0, buf1 @32768; epilogue overlays dead buf

    const int xcd = blockIdx.x & 7;
    const int idx = blockIdx.x >> 3;
    const int bmPerX = nbm >> 3;
    const int bm = xcd * bmPerX + (idx % bmPerX);
    const int strip = idx / bmPerX;
    const int bn0 = strip * NT;

    const int tid = threadIdx.x;
    const int lane = tid & 63;
    const int wid = tid >> 6;
    const int wr = wid >> 1, wc = wid & 1;
    const int brow = bm * 128 + wr * 64;
    const int l15 = lane & 15;
    const int lg  = lane >> 4;

    const float g = *gamma_p;
    const float two_s = 2.0f * g * 1.4426950408889634f;
    const float* ny = nrm + N;

    // A fragments persistent in registers (hi/lo, 2 k-steps x 4 mf)
    s16x8 ah[2][4], al[2][4];
    {
        const unsigned short* apan = xpk + (size_t)bm * 16384;   // 32KB panel
        #pragma unroll
        for (int ks = 0; ks < 2; ++ks) {
            const int kc = ks * 4 + lg;
            #pragma unroll
            for (int mf = 0; mf < 4; ++mf) {
                const int arow = wr * 64 + mf * 16 + l15;
                const int u = arow * 8 + (kc ^ (arow & 7));
                ah[ks][mf] = *(const s16x8*)(apan + (size_t)u * 8);
                al[ks][mf] = *(const s16x8*)(apan + (size_t)(u + 1024) * 8);
            }
        }
    }
    // A-row norms, persistent
    float xn[4][4];
    #pragma unroll
    for (int mf = 0; mf < 4; ++mf)
        #pragma unroll
        for (int j = 0; j < 4; ++j)
            xn[mf][j] = nrm[brow + mf * 16 + lg * 4 + j];

    // stage B panel for first tile into buf0
    {
        const char* src = (const char*)ypk + (size_t)bn0 * 32768;
        #pragma unroll
        for (int it = 0; it < 8; ++it) {
            const int local = it * 4096 + wid * 1024;
            __builtin_amdgcn_global_load_lds(
                (const __attribute__((address_space(1))) void*)(src + local + lane * 16),
                (__attribute__((address_space(3))) void*)(smem + local), 16, 0, 0);
        }
    }
    __builtin_amdgcn_sched_barrier(0);
    asm volatile("s_waitcnt vmcnt(0)" ::: "memory");
    __builtin_amdgcn_sched_barrier(0);
    __builtin_amdgcn_s_barrier();
    __builtin_amdgcn_sched_barrier(0);

    for (int i = 0; i < NT; ++i) {
        const int cur = i & 1;
        const int bn = bn0 + i;
        const int bcol = bn * 128 + wc * 64;

        // yn loads FIRST (oldest vmem of this iter -> their wait doesn't
        // force staging completion)
        float yn[4];
        #pragma unroll
        for (int nf = 0; nf < 4; ++nf)
            yn[nf] = ny[bcol + nf * 16 + l15];

        // issue next-tile staging into the other buffer
        if (i + 1 < NT) {
            const char* src = (const char*)ypk + (size_t)(bn + 1) * 32768;
            char* dstb = smem + (cur ^ 1) * 32768;
            #pragma unroll
            for (int it = 0; it < 8; ++it) {
                const int local = it * 4096 + wid * 1024;
                __builtin_amdgcn_global_load_lds(
                    (const __attribute__((address_space(1))) void*)(src + local + lane * 16),
                    (__attribute__((address_space(3))) void*)(dstb + local), 16, 0, 0);
            }
        }

        // MFMA from buf[cur] (staged last iter, waited at last iter's end)
        const char* bufb = smem + cur * 32768;
        f32x4 acc[4][4];
        #pragma unroll
        for (int a = 0; a < 4; ++a)
            #pragma unroll
            for (int b = 0; b < 4; ++b)
                #pragma unroll
                for (int e = 0; e < 4; ++e)
                    acc[a][b][e] = 0.0f;

        #pragma unroll
        for (int ks = 0; ks < 2; ++ks) {
            const int kc = ks * 4 + lg;
            s16x8 bh[4], bl[4];
            #pragma unroll
            for (int nf = 0; nf < 4; ++nf) {
                const int brw = wc * 64 + nf * 16 + l15;
                const int off = brw * 128 + ((kc ^ (brw & 7)) << 4);
                bh[nf] = *(const s16x8*)(bufb + off);
                bl[nf] = *(const s16x8*)(bufb + 16384 + off);
            }
            #pragma unroll
            for (int mf = 0; mf < 4; ++mf)
                #pragma unroll
                for (int nf = 0; nf < 4; ++nf) {
                    acc[mf][nf] = __builtin_amdgcn_mfma_f32_16x16x32_bf16(ah[ks][mf], bh[nf], acc[mf][nf], 0, 0, 0);
                    acc[mf][nf] = __builtin_amdgcn_mfma_f32_16x16x32_bf16(ah[ks][mf], bl[nf], acc[mf][nf], 0, 0, 0);
                    acc[mf][nf] = __builtin_amdgcn_mfma_f32_16x16x32_bf16(al[ks][mf], bh[nf], acc[mf][nf], 0, 0, 0);
                }
        }

        // all waves done reading buf[cur] -> safe to overlay bounce
        __builtin_amdgcn_sched_barrier(0);
        __builtin_amdgcn_s_barrier();
        __builtin_amdgcn_sched_barrier(0);

        // epilogue: exp -> LDS transpose bounce (dead buf[cur]) -> full-line stores
        float* wl = (float*)(smem + cur * 32768) + wid * 16 * LROW;   // 4x4.25KB
        #pragma unroll
        for (int mf = 0; mf < 4; ++mf) {
            #pragma unroll
            for (int nf = 0; nf < 4; ++nf) {
                const int c = nf * 16 + l15;
                #pragma unroll
                for (int j = 0; j < 4; ++j) {
                    const float d = fmaf(two_s, acc[mf][nf][j], xn[mf][j] + yn[nf]);
                    wl[(lg * 4 + j) * LROW + c] = EXP2F(d);
                }
            }
            #pragma unroll
            for (int t = 0; t < 4; ++t) {
                const int r = t * 4 + lg;
                f32x4 v = *(const f32x4*)&wl[r * LROW + l15 * 4];
                float* dst = out + (size_t)(brow + mf * 16 + r) * M + bcol + l15 * 4;
                *(f32x4*)dst = v;
            }
        }

        // counted wait: 16 newest ops are our stores -> staging (older) retired,
        // stores stay in flight across the barrier.
        __builtin_amdgcn_sched_barrier(0);
        asm volatile("s_waitcnt vmcnt(16)" ::: "memory");
        __builtin_amdgcn_sched_barrier(0);
        __builtin_amdgcn_s_barrier();
        __builtin_amdgcn_sched_barrier(0);
    }
}

// ---------------- Generic fallback (R7 main) ----------------
__global__ __launch_bounds__(256, 2) void rbf_main(
        const unsigned short* __restrict__ xpk, const unsigned short* __restrict__ ypk,
        const float* __restrict__ gamma_p, const float* __restrict__ nrm,
        float* __restrict__ out, int N, int M, int nbm, int nbn) {
    __shared__ char smem[65536];

    int bm, bn;
    const int nwg = nbm * nbn;
    if ((nwg & 7) == 0 && (nbm & 7) == 0) {
        const int xcd = blockIdx.x & 7;
        const int lo  = blockIdx.x >> 3;
        const int bmPerX = nbm >> 3;
        bn = lo / bmPerX;
        bm = xcd * bmPerX + (lo - bn * bmPerX);
    } else {
        bm = blockIdx.x / nbn;
        bn = blockIdx.x - bm * nbn;
    }

    const int tid = threadIdx.x;
    const int lane = tid & 63;
    const int wid = tid >> 6;
    const int wr = wid >> 1, wc = wid & 1;
    const int brow = bm * 128 + wr * 64;
    const int bcol = bn * 128 + wc * 64;
    const int l15 = lane & 15;
    const int lg  = lane >> 4;

    f32x4 acc[4][4];
    #pragma unroll
    for (int i = 0; i < 4; ++i)
        #pragma unroll
        for (int j = 0; j < 4; ++j)
            #pragma unroll
            for (int e = 0; e < 4; ++e)
                acc[i][j][e] = 0.0f;

    {
        const char* srcA = (const char*)xpk + (size_t)bm * 32768;
        const char* srcB = (const char*)ypk + (size_t)bn * 32768;
        #pragma unroll
        for (int it = 0; it < 16; ++it) {
            const int isB = it >> 3;
            const int local = (it & 7) * 4096 + wid * 1024;
            const char* src = (isB ? srcB : srcA) + local + lane * 16;
            char* dst = smem + isB * 32768 + local;
            __builtin_amdgcn_global_load_lds(
                (const __attribute__((address_space(1))) void*)src,
                (__attribute__((address_space(3))) void*)dst, 16, 0, 0);
        }
    }
    __syncthreads();

    s16x8 ah[4], al[4], bh[4], bl[4];
    #pragma unroll
    for (int k0 = 0; k0 < 64; k0 += 32) {
        const int kc = (k0 >> 3) + lg;
        #pragma unroll
        for (int mf = 0; mf < 4; ++mf) {
            const int arow = wr * 64 + mf * 16 + l15;
            const int off = arow * 128 + ((kc ^ (arow & 7)) << 4);
            ah[mf] = *(const s16x8*)(smem + off);
            al[mf] = *(const s16x8*)(smem + 16384 + off);
        }
        #pragma unroll
        for (int nf = 0; nf < 4; ++nf) {
            const int brw = wc * 64 + nf * 16 + l15;
            const int off = brw * 128 + ((kc ^ (brw & 7)) << 4);
            bh[nf] = *(const s16x8*)(smem + 32768 + off);
            bl[nf] = *(const s16x8*)(smem + 49152 + off);
        }
        #pragma unroll
        for (int mf = 0; mf < 4; ++mf)
            #pragma unroll
            for (int nf = 0; nf < 4; ++nf) {
                acc[mf][nf] = __builtin_amdgcn_mfma_f32_16x16x32_bf16(ah[mf], bh[nf], acc[mf][nf], 0, 0, 0);
                acc[mf][nf] = __builtin_amdgcn_mfma_f32_16x16x32_bf16(ah[mf], bl[nf], acc[mf][nf], 0, 0, 0);
                acc[mf][nf] = __builtin_amdgcn_mfma_f32_16x16x32_bf16(al[mf], bh[nf], acc[mf][nf], 0, 0, 0);
            }
    }
    __syncthreads();

    const float g = *gamma_p;
    const float two_s = 2.0f * g * 1.4426950408889634f;

    float yn[4];
    #pragma unroll
    for (int nf = 0; nf < 4; ++nf)
        yn[nf] = (nrm + N)[bcol + nf * 16 + l15];

    float* wl = (float*)smem + wid * 16 * LROW;
    #pragma unroll
    for (int mf = 0; mf < 4; ++mf) {
        float xn[4];
        #pragma unroll
        for (int j = 0; j < 4; ++j)
            xn[j] = nrm[brow + mf * 16 + lg * 4 + j];
        #pragma unroll
        for (int nf = 0; nf < 4; ++nf) {
            const int c = nf * 16 + l15;
            #pragma unroll
            for (int j = 0; j < 4; ++j) {
                const float d = fmaf(two_s, acc[mf][nf][j], xn[j] + yn[nf]);
                wl[(lg * 4 + j) * LROW + c] = EXP2F(d);
            }
        }
        #pragma unroll
        for (int t = 0; t < 4; ++t) {
            const int r = t * 4 + lg;
            f32x4 v = *(const f32x4*)&wl[r * LROW + l15 * 4];
            float* dst = out + (size_t)(brow + mf * 16 + r) * M + bcol + l15 * 4;
            *(f32x4*)dst = v;
        }
    }
}

// Fallback (ws too small): fully fused, no workspace.
__global__ __launch_bounds__(256, 2) void rbf_fused_nows(
        const float* __restrict__ x, const float* __restrict__ y,
        const float* __restrict__ gamma_p,
        float* __restrict__ out, int N, int M, int nbm, int nbn) {
    __shared__ char smem[65536];
    __shared__ float nrmAB[256];

    int bm, bn;
    const int nwg = nbm * nbn;
    if ((nwg & 7) == 0 && (nbm & 7) == 0) {
        const int xcd = blockIdx.x & 7;
        const int lo  = blockIdx.x >> 3;
        const int bmPerX = nbm >> 3;
        bn = lo / bmPerX;
        bm = xcd * bmPerX + (lo - bn * bmPerX);
    } else {
        bm = blockIdx.x / nbn;
        bn = blockIdx.x - bm * nbn;
    }

    const int tid = threadIdx.x;
    const int lane = tid & 63;
    const int wid = tid >> 6;
    const int wr = wid >> 1, wc = wid & 1;
    const int brow = bm * 128 + wr * 64;
    const int bcol = bn * 128 + wc * 64;
    const int l15 = lane & 15;
    const int lg  = lane >> 4;

    const float g = *gamma_p;
    const float negs = -g * 1.4426950408889634f;
    const float two_s = 2.0f * g * 1.4426950408889634f;

    f32x4 acc[4][4];
    #pragma unroll
    for (int i = 0; i < 4; ++i)
        #pragma unroll
        for (int j = 0; j < 4; ++j)
            #pragma unroll
            for (int e = 0; e < 4; ++e)
                acc[i][j][e] = 0.0f;

    {
        const float* srcx = x + (size_t)bm * 128 * 64;
        const float* srcy = y + (size_t)bn * 128 * 64;
        #pragma unroll
        for (int it = 0; it < 8; ++it) {
            const int u = it * 256 + tid;
            const int isy = it >> 2;
            const int v = u & 1023;
            const int row = v >> 3, kc = v & 7;
            const float* s = (isy ? srcy : srcx) + (size_t)row * 64 + kc * 8;
            f32x4 t0 = *(const f32x4*)s;
            f32x4 t1 = *(const f32x4*)(s + 4);
            s16x8 h, l;
            #pragma unroll
            for (int j = 0; j < 4; ++j) {
                unsigned short hb = bf16_rne(t0[j]);
                float hf = __uint_as_float((unsigned)hb << 16);
                h[j] = (short)hb; l[j] = (short)bf16_rne(t0[j] - hf);
                hb = bf16_rne(t1[j]);
                hf = __uint_as_float((unsigned)hb << 16);
                h[4+j] = (short)hb; l[4+j] = (short)bf16_rne(t1[j] - hf);
            }
            const int dst = (isy << 15) + row * 128 + ((kc ^ (row & 7)) << 4);
            *(s16x8*)(smem + dst) = h;
            *(s16x8*)(smem + dst + 16384) = l;
            float sn = t0[0]*t0[0] + t0[1]*t0[1] + t0[2]*t0[2] + t0[3]*t0[3]
                     + t1[0]*t1[0] + t1[1]*t1[1] + t1[2]*t1[2] + t1[3]*t1[3];
            sn += __shfl_xor(sn, 1);
            sn += __shfl_xor(sn, 2);
            sn += __shfl_xor(sn, 4);
            if (kc == 0) nrmAB[(isy << 7) + row] = negs * sn;
        }
    }
    __syncthreads();

    s16x8 ah[4], al[4], bh[4], bl[4];
    #pragma unroll
    for (int k0 = 0; k0 < 64; k0 += 32) {
        const int kc = (k0 >> 3) + lg;
        #pragma unroll
        for (int mf = 0; mf < 4; ++mf) {
            const int arow = wr * 64 + mf * 16 + l15;
            const int off = arow * 128 + ((kc ^ (arow & 7)) << 4);
            ah[mf] = *(const s16x8*)(smem + off);
            al[mf] = *(const s16x8*)(smem + 16384 + off);
        }
        #pragma unroll
        for (int nf = 0; nf < 4; ++nf) {
            const int brw = wc * 64 + nf * 16 + l15;
            const int off = brw * 128 + ((kc ^ (brw & 7)) << 4);
            bh[nf] = *(const s16x8*)(smem + 32768 + off);
            bl[nf] = *(const s16x8*)(smem + 49152 + off);
        }
        #pragma unroll
        for (int mf = 0; mf < 4; ++mf)
            #pragma unroll
            for (int nf = 0; nf < 4; ++nf) {
                acc[mf][nf] = __builtin_amdgcn_mfma_f32_16x16x32_bf16(ah[mf], bh[nf], acc[mf][nf], 0, 0, 0);
                acc[mf][nf] = __builtin_amdgcn_mfma_f32_16x16x32_bf16(ah[mf], bl[nf], acc[mf][nf], 0, 0, 0);
                acc[mf][nf] = __builtin_amdgcn_mfma_f32_16x16x32_bf16(al[mf], bh[nf], acc[mf][nf], 0, 0, 0);
            }
    }
    __syncthreads();

    float yn[4];
    #pragma unroll
    for (int nf = 0; nf < 4; ++nf)
        yn[nf] = nrmAB[128 + wc * 64 + nf * 16 + l15];

    float* wl = (float*)smem + wid * 16 * LROW;
    #pragma unroll
    for (int mf = 0; mf < 4; ++mf) {
        float xn[4];
        #pragma unroll
        for (int j = 0; j < 4; ++j)
            xn[j] = nrmAB[wr * 64 + mf * 16 + lg * 4 + j];
        #pragma unroll
        for (int nf = 0; nf < 4; ++nf) {
            const int c = nf * 16 + l15;
            #pragma unroll
            for (int j = 0; j < 4; ++j) {
                const float d = fmaf(two_s, acc[mf][nf][j], xn[j] + yn[nf]);
                wl[(lg * 4 + j) * LROW + c] = EXP2F(d);
            }
        }
        #pragma unroll
        for (int t = 0; t < 4; ++t) {
            const int r = t * 4 + lg;
            f32x4 v = *(const f32x4*)&wl[r * LROW + l15 * 4];
            float* dst = out + (size_t)(brow + mf * 16 + r) * M + bcol + l15 * 4;
            *(f32x4*)dst = v;
        }
    }
}

extern "C" void kernel_launch(void* const* d_in, const int* in_sizes, int n_in,
                              void* d_out, int out_size, void* d_ws, size_t ws_size,
                              hipStream_t stream) {
    const float* x = (const float*)d_in[0];
    const float* y = (const float*)d_in[1];
    const float* gamma_p = (const float*)d_in[2];
    float* out = (float*)d_out;

    const int D = 64;
    const int N = in_sizes[0] / D;
    const int M = in_sizes[1] / D;
    const int nbm = N / 128, nbn = M / 128;

    // ws layout: [nrm: (N+M) f32][xpk: N*128 u16][ypk: M*128 u16]
    char* wsb = (char*)d_ws;
    float* nrm = (float*)wsb;
    size_t off = ((size_t)(N + M) * 4 + 15) & ~(size_t)15;
    unsigned short* xpk = (unsigned short*)(wsb + off); off += (size_t)N * 128 * 2;
    unsigned short* ypk = (unsigned short*)(wsb + off); off += (size_t)M * 128 * 2;

    if (ws_size >= off) {
        const int rows = N + M;
        rbf_pack<<<(rows + 31) / 32, 256, 0, stream>>>(x, y, gamma_p, nrm, xpk, ypk, N, M);
        if ((nbm % 8) == 0 && (nbn % NT) == 0) {
            const int grid = nbm * (nbn / NT);
            rbf_persist<<<grid, 256, 0, stream>>>(xpk, ypk, gamma_p, nrm, out, N, M, nbm, nbn);
        } else {
            rbf_main<<<nbm * nbn, 256, 0, stream>>>(xpk, ypk, gamma_p, nrm, out, N, M, nbm, nbn);
        }
    } else {
        rbf_fused_nows<<<nbm * nbn, 256, 0, stream>>>(x, y, gamma_p, out, N, M, nbm, nbn);
    }
}